// Round 12
// baseline (1355.646 us; speedup 1.0000x reference)
//
#include <hip/hip_runtime.h>
#include <cmath>

// Decoder: 3-layer GRU (B=16, H=2048, E=128) + vocab projection (V=32000) + log_softmax.
// Memory-bound: 516 MB fp32 weights streamed once.
//
// R1-R11: seven GEMV structures converge to ~3 TB/s W-read. Common defects:
// (a) all k-sliced designs read W as 8KB-strided bursts (fill kernels, which
// hit 7 TB/s, sweep contiguously); (b) the one row-contiguous design (R3) paid
// 16 ds_read_b128 per KB W -> LDS-pipe cap ~3.3 TB/s. This round fixes both:
// wave owns NR CONSECUTIVE rows, sweeps k-fastest (contiguous streams); x
// staged once in 128KB LDS; one x-slice (16 ds_read) serves NR KB of W
// (NR=3: 64 LDS-cyc/KB < 93 HBM budget); acc over full row, ONE fold at end;
// W prefetched 2 deep (64 KB/CU in flight). ~180 VGPR, no spill.

#define BB 16
#define HH 2048
#define EE 128
#define VV 32000
#define G3H (3 * HH)

__device__ __forceinline__ void fma4(float& a, const float4 w, const float4 x) {
  a = fmaf(w.x, x.x, a); a = fmaf(w.y, x.y, a);
  a = fmaf(w.z, x.z, a); a = fmaf(w.w, x.w, a);
}

// fold two slot-values into one, halving slot count; lane bit m selects half.
__device__ __forceinline__ float foldpair(float a, float b, int m, int lane) {
  float t = (lane & m) ? a : b;     // value we send
  t = __shfl_xor(t, m, 64);
  return ((lane & m) ? b : a) + t;  // value we keep + partner's
}

// static-index select (no runtime-indexed register arrays)
__device__ __forceinline__ float sel16(const float a[16], int i) {
  float s0 = (i & 1) ? a[1]  : a[0];
  float s1 = (i & 1) ? a[3]  : a[2];
  float s2 = (i & 1) ? a[5]  : a[4];
  float s3 = (i & 1) ? a[7]  : a[6];
  float s4 = (i & 1) ? a[9]  : a[8];
  float s5 = (i & 1) ? a[11] : a[10];
  float s6 = (i & 1) ? a[13] : a[12];
  float s7 = (i & 1) ? a[15] : a[14];
  float t0 = (i & 2) ? s1 : s0;
  float t1 = (i & 2) ? s3 : s2;
  float t2 = (i & 2) ? s5 : s4;
  float t3 = (i & 2) ? s7 : s6;
  float u0 = (i & 4) ? t1 : t0;
  float u1 = (i & 4) ? t3 : t2;
  return (i & 8) ? u1 : u0;
}

// stage x(16,2048) fp32 into LDS, 512 threads, coalesced float4
__device__ __forceinline__
void stage_x(float* sx, const float* __restrict__ x, int tid) {
  #pragma unroll
  for (int i = 0; i < 16; ++i) {
    const int f = i * 512 + tid;
    *(float4*)(sx + f * 4) = *(const float4*)(x + f * 4);
  }
}

// NR consecutive rows x 16 batches over DIM=2048, contiguous k-sweep.
// Lane L covers k = it*256 + L*4; acc over full rows; single fold at end.
template<int NR, bool BIAS>
__device__ __forceinline__
void sweep_rows(const float* sx, const float* __restrict__ W,
                const float* __restrict__ bias, float* __restrict__ dst,
                int ldd, int r0, int lane)
{
  const int kb = lane * 4;
  const float* Wr = W + (size_t)r0 * HH + kb;

  float acc[64];
  #pragma unroll
  for (int i = 0; i < 64; ++i) acc[i] = 0.f;

  // 2-deep W prefetch pipeline
  float4 wbuf0[NR], wbuf1[NR];
  #pragma unroll
  for (int r = 0; r < NR; ++r) wbuf0[r] = *(const float4*)(Wr + (size_t)r * HH);
  #pragma unroll
  for (int r = 0; r < NR; ++r) wbuf1[r] = *(const float4*)(Wr + (size_t)r * HH + 256);

  #pragma unroll
  for (int it = 0; it < 8; ++it) {
    float4 xv[16];
    #pragma unroll
    for (int b = 0; b < 16; ++b)
      xv[b] = *(const float4*)(sx + b * HH + it * 256 + kb);
    float4 w[NR];
    #pragma unroll
    for (int r = 0; r < NR; ++r) w[r] = (it & 1) ? wbuf1[r] : wbuf0[r];
    if (it < 6) {
      #pragma unroll
      for (int r = 0; r < NR; ++r) {
        const float4 nw = *(const float4*)(Wr + (size_t)r * HH + (it + 2) * 256);
        if (it & 1) wbuf1[r] = nw; else wbuf0[r] = nw;
      }
    }
    #pragma unroll
    for (int r = 0; r < NR; ++r)
      #pragma unroll
      for (int b = 0; b < 16; ++b)
        fma4(acc[r * 16 + b], w[r], xv[b]);
  }

  // fold 64 slots -> 1 per lane (slot = [r*16+b])
  #pragma unroll
  for (int j = 0; j < 32; ++j) acc[j] = foldpair(acc[j], acc[j + 32], 1, lane);
  #pragma unroll
  for (int j = 0; j < 16; ++j) acc[j] = foldpair(acc[j], acc[j + 16], 2, lane);
  #pragma unroll
  for (int j = 0; j < 8; ++j)  acc[j] = foldpair(acc[j], acc[j + 8], 4, lane);
  #pragma unroll
  for (int j = 0; j < 4; ++j)  acc[j] = foldpair(acc[j], acc[j + 4], 8, lane);
  #pragma unroll
  for (int j = 0; j < 2; ++j)  acc[j] = foldpair(acc[j], acc[j + 2], 16, lane);
  acc[0] = foldpair(acc[0], acc[1], 32, lane);

  // lane L holds slot idx = bitrev6(L)
  const int idx = ((lane & 1) << 5) | ((lane & 2) << 3) | ((lane & 4) << 1)
                | ((lane & 8) >> 1) | ((lane & 16) >> 3) | ((lane & 32) >> 5);
  const int r = idx >> 4;
  const int b = idx & 15;
  if (idx < NR * 16) {
    float o = acc[0];
    if (BIAS) o += bias[r0 + r];
    dst[(size_t)b * ldd + r0 + r] = o;
  }
}

// GRU matrix sweep: blocks [0,256): dA = xA @ WA^T; [256,512): dB = xB @ WB^T.
// 512 thr = 8 waves; block owns 24 consecutive rows (192 KB contiguous W).
__global__ __launch_bounds__(512, 2)
void sweep_gru(const float* __restrict__ xA, const float* __restrict__ xB,
               const float* __restrict__ WA, const float* __restrict__ WB,
               float* __restrict__ dA, float* __restrict__ dB)
{
  __shared__ float sx[BB * HH];   // 128 KB
  const int tid  = threadIdx.x;
  const int lane = tid & 63;
  const int wv   = tid >> 6;
  const bool second = blockIdx.x >= 256;
  const float* x = second ? xB : xA;
  const float* W = second ? WB : WA;
  float* d       = second ? dB : dA;
  const int bx   = second ? blockIdx.x - 256 : blockIdx.x;

  stage_x(sx, x, tid);
  __syncthreads();
  sweep_rows<3, false>(sx, W, nullptr, d, G3H, bx * 24 + wv * 3, lane);
}

// Layer-0 input GEMV (3MB, DIM=128): old verified kkrg path.
__global__ __launch_bounds__(256, 2)
void gru_ih0(const float* __restrict__ emb, const int* __restrict__ tokens,
             const float* __restrict__ Wih0, float* __restrict__ gi)
{
  const int tid  = threadIdx.x;
  const int lane = tid & 63;
  const int kk   = lane & 15;
  const int rg   = lane >> 4;
  const int u    = blockIdx.x * 4 + (tid >> 6);
  const int row0 = u * 12 + rg * 3;
  float acc[3][16];
  #pragma unroll
  for (int r = 0; r < 3; ++r)
    #pragma unroll
    for (int b = 0; b < 16; ++b) acc[r][b] = 0.f;

  #pragma unroll
  for (int it = 0; it < 2; ++it) {
    const int k = it * 64 + kk * 4;
    const float4 w0 = *(const float4*)(Wih0 + (size_t)row0 * EE + k);
    const float4 w1 = *(const float4*)(Wih0 + (size_t)(row0 + 1) * EE + k);
    const float4 w2 = *(const float4*)(Wih0 + (size_t)(row0 + 2) * EE + k);
    #pragma unroll
    for (int b = 0; b < 16; ++b) {
      float4 xv = *(const float4*)(emb + (size_t)tokens[b] * EE + k);
      xv.x = fmaxf(xv.x, 0.f); xv.y = fmaxf(xv.y, 0.f);
      xv.z = fmaxf(xv.z, 0.f); xv.w = fmaxf(xv.w, 0.f);
      fma4(acc[0][b], w0, xv);
      fma4(acc[1][b], w1, xv);
      fma4(acc[2][b], w2, xv);
    }
  }
  #pragma unroll
  for (int r = 0; r < 3; ++r) {
    #pragma unroll
    for (int b = 0; b < 16; ++b) {
      float a = acc[r][b];
      a += __shfl_xor(a, 1, 64);
      a += __shfl_xor(a, 2, 64);
      a += __shfl_xor(a, 4, 64);
      a += __shfl_xor(a, 8, 64);
      acc[r][b] = a;
    }
  }
  #pragma unroll
  for (int r = 0; r < 3; ++r)
    gi[(size_t)kk * G3H + row0 + r] = sel16(acc[r], kk);
}

// Gate math: h' = (1-z)*n + z*h. B*H threads.
__global__ __launch_bounds__(256)
void gru_epi(const float* __restrict__ gi, const float* __restrict__ gh,
             const float* __restrict__ bih, const float* __restrict__ bhh,
             const float* __restrict__ hprev, float* __restrict__ hout)
{
  const int idx = blockIdx.x * 256 + threadIdx.x;
  const int j = idx & (HH - 1);
  const size_t base = (size_t)(idx >> 11) * G3H;
  const float ir  = gi[base + j]          + bih[j];
  const float iz  = gi[base + HH + j]     + bih[HH + j];
  const float in_ = gi[base + 2 * HH + j] + bih[2 * HH + j];
  const float hr  = gh[base + j]          + bhh[j];
  const float hz  = gh[base + HH + j]     + bhh[HH + j];
  const float hn  = gh[base + 2 * HH + j] + bhh[2 * HH + j];
  const float r = 1.f / (1.f + expf(-(ir + hr)));
  const float z = 1.f / (1.f + expf(-(iz + hz)));
  const float n = tanhf(in_ + r * hn);
  hout[idx] = (1.f - z) * n + z * hprev[idx];
}

// Vocab projection: 250 blocks x 128 consecutive rows; wave = 16 rows = 4 quads.
__global__ __launch_bounds__(512, 2)
void sweep_out(const float* __restrict__ h2, const float* __restrict__ Wout,
               const float* __restrict__ bout, float* __restrict__ logits)
{
  __shared__ float sx[BB * HH];
  const int tid  = threadIdx.x;
  const int lane = tid & 63;
  const int wv   = tid >> 6;

  stage_x(sx, h2, tid);
  __syncthreads();

  const int base = blockIdx.x * 128 + wv * 16;
  #pragma unroll
  for (int t = 0; t < 4; ++t)
    sweep_rows<4, true>(sx, Wout, bout, logits, VV, base + t * 4, lane);
}

// In-place log_softmax over each of the 16 rows (32000 wide).
__global__ __launch_bounds__(1024)
void lsm_kernel(float* __restrict__ logp)
{
  const int b   = blockIdx.x;
  const int tid = threadIdx.x;
  float* row = logp + (size_t)b * VV;
  const float4* r4 = (const float4*)row;
  __shared__ float red[16];
  const int wv = tid >> 6, ln = tid & 63;

  float m = -3.4e38f;
  for (int i = tid; i < VV / 4; i += 1024) {
    float4 v = r4[i];
    m = fmaxf(m, fmaxf(fmaxf(v.x, v.y), fmaxf(v.z, v.w)));
  }
  #pragma unroll
  for (int s = 1; s < 64; s <<= 1) m = fmaxf(m, __shfl_xor(m, s, 64));
  if (ln == 0) red[wv] = m;
  __syncthreads();
  if (tid == 0) {
    float mm = red[0];
    for (int w = 1; w < 16; ++w) mm = fmaxf(mm, red[w]);
    red[0] = mm;
  }
  __syncthreads();
  const float M = red[0];
  __syncthreads();

  float s = 0.f;
  for (int i = tid; i < VV / 4; i += 1024) {
    float4 v = r4[i];
    s += expf(v.x - M) + expf(v.y - M) + expf(v.z - M) + expf(v.w - M);
  }
  #pragma unroll
  for (int t = 1; t < 64; t <<= 1) s += __shfl_xor(s, t, 64);
  if (ln == 0) red[wv] = s;
  __syncthreads();
  if (tid == 0) {
    float ss = 0.f;
    for (int w = 0; w < 16; ++w) ss += red[w];
    red[0] = M + logf(ss);
  }
  __syncthreads();
  const float L = red[0];

  float4* w4 = (float4*)row;
  for (int i = tid; i < VV / 4; i += 1024) {
    float4 v = r4[i];
    v.x -= L; v.y -= L; v.z -= L; v.w -= L;
    w4[i] = v;
  }
}

extern "C" void kernel_launch(void* const* d_in, const int* in_sizes, int n_in,
                              void* d_out, int out_size, void* d_ws, size_t ws_size,
                              hipStream_t stream)
{
  const int*   tokens = (const int*)d_in[0];
  const float* hidden = (const float*)d_in[1]; // (3,B,H)
  const float* emb    = (const float*)d_in[2]; // (V,E)
  const float* Wih0 = (const float*)d_in[3];
  const float* Whh0 = (const float*)d_in[4];
  const float* bih0 = (const float*)d_in[5];
  const float* bhh0 = (const float*)d_in[6];
  const float* Wih1 = (const float*)d_in[7];
  const float* Whh1 = (const float*)d_in[8];
  const float* bih1 = (const float*)d_in[9];
  const float* bhh1 = (const float*)d_in[10];
  const float* Wih2 = (const float*)d_in[11];
  const float* Whh2 = (const float*)d_in[12];
  const float* bih2 = (const float*)d_in[13];
  const float* bhh2 = (const float*)d_in[14];
  const float* Wout = (const float*)d_in[15];
  const float* bout = (const float*)d_in[16];

  float* outp = (float*)d_out;
  float* logp = outp;                       // (B,V)
  float* hnew = outp + (size_t)BB * VV;     // (3,B,H)
  float* h0 = hnew;
  float* h1 = hnew + BB * HH;
  float* h2 = hnew + 2 * BB * HH;

  float* gi = (float*)d_ws;                 // (B,3H)
  float* gh = gi + (size_t)BB * G3H;        // (B,3H)

  gru_ih0<<<128, 256, 0, stream>>>(emb, tokens, Wih0, gi);
  sweep_gru<<<256, 512, 0, stream>>>(hidden, nullptr, Whh0, nullptr, gh, nullptr);
  gru_epi<<<128, 256, 0, stream>>>(gi, gh, bih0, bhh0, hidden, h0);
  sweep_gru<<<512, 512, 0, stream>>>(h0, hidden + BB * HH, Wih1, Whh1, gi, gh);
  gru_epi<<<128, 256, 0, stream>>>(gi, gh, bih1, bhh1, hidden + BB * HH, h1);
  sweep_gru<<<512, 512, 0, stream>>>(h1, hidden + 2 * BB * HH, Wih2, Whh2, gi, gh);
  gru_epi<<<128, 256, 0, stream>>>(gi, gh, bih2, bhh2, hidden + 2 * BB * HH, h2);
  sweep_out<<<250, 512, 0, stream>>>(h2, Wout, bout, logp);
  lsm_kernel<<<16, 1024, 0, stream>>>(logp);
}

// Round 13
// 225.207 us; speedup vs baseline: 6.0195x; 6.0195x over previous
//
#include <hip/hip_runtime.h>
#include <cmath>

// Decoder: 3-layer GRU (B=16, H=2048, E=128) + vocab projection (V=32000) + log_softmax.
// Memory-bound: 516 MB fp32 weights streamed once.
//
// R1-R12 post-mortem: every design computed with an EMPTY read queue (even R11's
// glds loop drained vmcnt(0) before computing). This round = R11 verbatim EXCEPT
// gemv_stream is double-buffered with counted vmcnt: issue batch m+1 -> wait
// vmcnt(8) (batch m done, batch m+1 still in flight) -> sched_barrier -> compute.
// Wave always has 8KB in flight; 8 waves/CU = 64KB/CU continuous.
// R12 lesson (repeat of R6): 512-thr blocks need launch_bounds(512,1) for the
// 256 cap; here we use 256-thr blocks with (256,2).

#define BB 16
#define HH 2048
#define EE 128
#define VV 32000
#define G3H (3 * HH)

__device__ __forceinline__ void fma4(float& a, const float4 w, const float4 x) {
  a = fmaf(w.x, x.x, a); a = fmaf(w.y, x.y, a);
  a = fmaf(w.z, x.z, a); a = fmaf(w.w, x.w, a);
}

__device__ __forceinline__ void glds16(const float* g, float* l) {
  __builtin_amdgcn_global_load_lds(
      (__attribute__((address_space(1))) void*)(g),
      (__attribute__((address_space(3))) void*)(l), 16, 0, 0);
}

// fold two slot-values into one, halving slot count; lane bit m selects half.
__device__ __forceinline__ float foldpair(float a, float b, int m, int lane) {
  float t = (lane & m) ? a : b;     // value we send
  t = __shfl_xor(t, m, 64);
  return ((lane & m) ? b : a) + t;  // value we keep + partner's
}

// static-index select (no runtime-indexed register arrays)
__device__ __forceinline__ float sel16(const float a[16], int i) {
  float s0 = (i & 1) ? a[1]  : a[0];
  float s1 = (i & 1) ? a[3]  : a[2];
  float s2 = (i & 1) ? a[5]  : a[4];
  float s3 = (i & 1) ? a[7]  : a[6];
  float s4 = (i & 1) ? a[9]  : a[8];
  float s5 = (i & 1) ? a[11] : a[10];
  float s6 = (i & 1) ? a[13] : a[12];
  float s7 = (i & 1) ? a[15] : a[14];
  float t0 = (i & 2) ? s1 : s0;
  float t1 = (i & 2) ? s3 : s2;
  float t2 = (i & 2) ? s5 : s4;
  float t3 = (i & 2) ? s7 : s6;
  float u0 = (i & 4) ? t1 : t0;
  float u1 = (i & 4) ? t3 : t2;
  return (i & 8) ? u1 : u0;
}

// issue 8 consecutive W row-slices (1KB each) into an LDS buffer, fire-and-forget
__device__ __forceinline__
void issue8(const float* __restrict__ W, int row0, int ko, float* buf) {
  #pragma unroll
  for (int r = 0; r < 8; ++r)
    glds16(W + (size_t)(row0 + r) * HH + ko, buf + r * 256);
}

// k-sliced streaming GEMV, double-buffered. Wave owns slice (256 k) and
// NU*8 consecutive rows. x-slice held in 64 VGPRs. Writes k-partials to planes.
template<int NU>
__device__ __forceinline__
void gemv_stream(const float* __restrict__ x,    // (16, HH)
                 const float* __restrict__ W,    // (R, HH)
                 float* __restrict__ planes,     // (8, 16, R)
                 int R, int slice, int row0,
                 int lane, float* lds)           // wave-private 2 x 2048 floats
{
  const int ko = slice * 256 + lane * 4;
  float4 xv[16];
  #pragma unroll
  for (int b = 0; b < 16; ++b)
    xv[b] = *(const float4*)(x + b * HH + ko);
  asm volatile("s_waitcnt vmcnt(0)" ::: "memory");   // drain x loads

  const int idx = ((lane & 1) << 4) | ((lane & 2) << 2) | (lane & 4)
                | ((lane & 8) >> 2) | ((lane & 16) >> 4);
  const int rr = idx >> 4;          // 2 rows per fold group
  const int bb = idx & 15;          // 16 batches

  issue8(W, row0, ko, lds);         // prime buf0

  for (int m = 0; m < NU; ++m) {
    float* cur = (m & 1) ? lds + 2048 : lds;
    float* nxt = (m & 1) ? lds : lds + 2048;
    if (m + 1 < NU) {
      issue8(W, row0 + (m + 1) * 8, ko, nxt);            // keep 8KB in flight
      asm volatile("s_waitcnt vmcnt(8)" ::: "memory");   // wait batch m only
    } else {
      asm volatile("s_waitcnt vmcnt(0)" ::: "memory");
    }
    __builtin_amdgcn_sched_barrier(0);

    #pragma unroll
    for (int g = 0; g < 4; ++g) {   // 2-row groups
      float acc[32];
      #pragma unroll
      for (int i = 0; i < 32; ++i) acc[i] = 0.f;
      const float4 w0 = *(const float4*)(cur + (g * 2 + 0) * 256 + lane * 4);
      const float4 w1 = *(const float4*)(cur + (g * 2 + 1) * 256 + lane * 4);
      #pragma unroll
      for (int b = 0; b < 16; ++b) {
        fma4(acc[b],      w0, xv[b]);
        fma4(acc[16 + b], w1, xv[b]);
      }
      #pragma unroll
      for (int j = 0; j < 16; ++j) acc[j] = foldpair(acc[j], acc[j + 16], 1, lane);
      #pragma unroll
      for (int j = 0; j < 8; ++j)  acc[j] = foldpair(acc[j], acc[j + 8], 2, lane);
      #pragma unroll
      for (int j = 0; j < 4; ++j)  acc[j] = foldpair(acc[j], acc[j + 4], 4, lane);
      #pragma unroll
      for (int j = 0; j < 2; ++j)  acc[j] = foldpair(acc[j], acc[j + 2], 8, lane);
      acc[0] = foldpair(acc[0], acc[1], 16, lane);
      acc[0] += __shfl_xor(acc[0], 32, 64);
      if (lane < 32)
        planes[(size_t)(slice * 16 + bb) * R + row0 + m * 8 + g * 2 + rr] = acc[0];
    }
  }
}

// Layer 0: blocks [0,128): gi_flat = relu(emb[tok]) @ Wih0^T (3MB, old path);
//          blocks [128,384): ghP planes = hprev @ Whh0^T (50MB, streamed).
__global__ __launch_bounds__(256, 2)
void gru_l0(const float* __restrict__ emb, const int* __restrict__ tokens,
            const float* __restrict__ hprev,
            const float* __restrict__ Wih0, const float* __restrict__ Whh0,
            float* __restrict__ gi_flat, float* __restrict__ ghP)
{
  __shared__ float lds[4 * 4096];   // 64 KB: 4 waves x 2 bufs x 2048
  const int tid  = threadIdx.x;
  const int lane = tid & 63;
  const int wv   = tid >> 6;
  const int bx   = blockIdx.x;

  if (bx < 128) {
    const int kk = lane & 15;
    const int rg = lane >> 4;
    const int u  = bx * 4 + wv;
    const int row0 = u * 12 + rg * 3;
    float acc[3][16];
    #pragma unroll
    for (int r = 0; r < 3; ++r)
      #pragma unroll
      for (int b = 0; b < 16; ++b) acc[r][b] = 0.f;

    #pragma unroll
    for (int it = 0; it < 2; ++it) {
      const int k = it * 64 + kk * 4;
      const float4 w0 = *(const float4*)(Wih0 + (size_t)row0 * EE + k);
      const float4 w1 = *(const float4*)(Wih0 + (size_t)(row0 + 1) * EE + k);
      const float4 w2 = *(const float4*)(Wih0 + (size_t)(row0 + 2) * EE + k);
      #pragma unroll
      for (int b = 0; b < 16; ++b) {
        float4 xv = *(const float4*)(emb + (size_t)tokens[b] * EE + k);
        xv.x = fmaxf(xv.x, 0.f); xv.y = fmaxf(xv.y, 0.f);
        xv.z = fmaxf(xv.z, 0.f); xv.w = fmaxf(xv.w, 0.f);
        fma4(acc[0][b], w0, xv);
        fma4(acc[1][b], w1, xv);
        fma4(acc[2][b], w2, xv);
      }
    }
    #pragma unroll
    for (int r = 0; r < 3; ++r) {
      #pragma unroll
      for (int b = 0; b < 16; ++b) {
        float a = acc[r][b];
        a += __shfl_xor(a, 1, 64);
        a += __shfl_xor(a, 2, 64);
        a += __shfl_xor(a, 4, 64);
        a += __shfl_xor(a, 8, 64);
        acc[r][b] = a;
      }
    }
    #pragma unroll
    for (int r = 0; r < 3; ++r)
      gi_flat[(size_t)kk * G3H + row0 + r] = sel16(acc[r], kk);
  } else {
    const int w = (bx - 128) * 4 + wv;   // [0,1024): slice = w>>7, part = w&127
    gemv_stream<6>(hprev, Whh0, ghP, G3H, w >> 7, (w & 127) * 48,
                   lane, lds + wv * 4096);
  }
}

// Layers 1/2: blocks [0,256): giP = xprev @ Wih^T; [256,512): ghP = hl @ Whh^T.
__global__ __launch_bounds__(256, 2)
void gru_l12(const float* __restrict__ xprev, const float* __restrict__ hl,
             const float* __restrict__ Wih, const float* __restrict__ Whh,
             float* __restrict__ giP, float* __restrict__ ghP)
{
  __shared__ float lds[4 * 4096];
  const int lane = threadIdx.x & 63;
  const int wv   = threadIdx.x >> 6;
  const int bx   = blockIdx.x;
  if (bx < 256) {
    const int w = bx * 4 + wv;
    gemv_stream<6>(xprev, Wih, giP, G3H, w >> 7, (w & 127) * 48,
                   lane, lds + wv * 4096);
  } else {
    const int w = (bx - 256) * 4 + wv;
    gemv_stream<6>(hl, Whh, ghP, G3H, w >> 7, (w & 127) * 48,
                   lane, lds + wv * 4096);
  }
}

// Gate math; gi from flat (layer 0) or 8 planes (layers 1/2); gh from 8 planes.
template<bool GI8>
__global__ __launch_bounds__(256)
void gru_epi(const float* __restrict__ gi_flat, const float* __restrict__ giP,
             const float* __restrict__ ghP,
             const float* __restrict__ bih, const float* __restrict__ bhh,
             const float* __restrict__ hprev, float* __restrict__ hout)
{
  const int idx = blockIdx.x * 256 + threadIdx.x;
  const int j = idx & (HH - 1);
  const int b = idx >> 11;
  float ir, iz, in_;
  if (GI8) {
    ir = 0.f; iz = 0.f; in_ = 0.f;
    #pragma unroll
    for (int s = 0; s < 8; ++s) {
      const size_t base = (size_t)(s * 16 + b) * G3H;
      ir  += giP[base + j];
      iz  += giP[base + HH + j];
      in_ += giP[base + 2 * HH + j];
    }
  } else {
    const size_t base = (size_t)b * G3H;
    ir  = gi_flat[base + j];
    iz  = gi_flat[base + HH + j];
    in_ = gi_flat[base + 2 * HH + j];
  }
  float hr = 0.f, hz = 0.f, hn = 0.f;
  #pragma unroll
  for (int s = 0; s < 8; ++s) {
    const size_t base = (size_t)(s * 16 + b) * G3H;
    hr += ghP[base + j];
    hz += ghP[base + HH + j];
    hn += ghP[base + 2 * HH + j];
  }
  ir += bih[j]; iz += bih[HH + j]; in_ += bih[2 * HH + j];
  hr += bhh[j]; hz += bhh[HH + j]; hn += bhh[2 * HH + j];
  const float r = 1.f / (1.f + expf(-(ir + hr)));
  const float z = 1.f / (1.f + expf(-(iz + hz)));
  const float n = tanhf(in_ + r * hn);
  hout[idx] = (1.f - z) * n + z * hprev[idx];
}

// Vocab projection partials: 2000 waves = 8 slices x 250 parts x 128 rows.
__global__ __launch_bounds__(256, 2)
void out_kernel(const float* __restrict__ h2, const float* __restrict__ Wout,
                float* __restrict__ opP)
{
  __shared__ float lds[4 * 4096];
  const int lane = threadIdx.x & 63;
  const int wv   = threadIdx.x >> 6;
  const int w = blockIdx.x * 4 + wv;      // [0,2000)
  const int slice = w / 250;
  const int part  = w % 250;
  gemv_stream<16>(h2, Wout, opP, VV, slice, part * 128, lane, lds + wv * 4096);
}

// Sum 8 plane-partials + bias -> logits, then in-place log_softmax per row.
__global__ __launch_bounds__(1024)
void lsm_kernel(const float* __restrict__ opP, const float* __restrict__ bout,
                float* __restrict__ logp)
{
  const int b   = blockIdx.x;
  const int tid = threadIdx.x;
  float* row = logp + (size_t)b * VV;
  __shared__ float red[16];
  const int wv = tid >> 6, ln = tid & 63;

  float m = -3.4e38f;
  for (int i = tid; i < VV / 4; i += 1024) {
    float4 a = ((const float4*)bout)[i];
    #pragma unroll
    for (int s = 0; s < 8; ++s) {
      const float4 p = ((const float4*)(opP + (size_t)(s * 16 + b) * VV))[i];
      a.x += p.x; a.y += p.y; a.z += p.z; a.w += p.w;
    }
    ((float4*)row)[i] = a;
    m = fmaxf(m, fmaxf(fmaxf(a.x, a.y), fmaxf(a.z, a.w)));
  }
  #pragma unroll
  for (int s = 1; s < 64; s <<= 1) m = fmaxf(m, __shfl_xor(m, s, 64));
  if (ln == 0) red[wv] = m;
  __syncthreads();
  if (tid == 0) {
    float mm = red[0];
    for (int w = 1; w < 16; ++w) mm = fmaxf(mm, red[w]);
    red[0] = mm;
  }
  __syncthreads();
  const float M = red[0];
  __syncthreads();

  float s = 0.f;
  for (int i = tid; i < VV / 4; i += 1024) {
    float4 v = ((const float4*)row)[i];
    s += expf(v.x - M) + expf(v.y - M) + expf(v.z - M) + expf(v.w - M);
  }
  #pragma unroll
  for (int t = 1; t < 64; t <<= 1) s += __shfl_xor(s, t, 64);
  if (ln == 0) red[wv] = s;
  __syncthreads();
  if (tid == 0) {
    float ss = 0.f;
    for (int w = 0; w < 16; ++w) ss += red[w];
    red[0] = M + logf(ss);
  }
  __syncthreads();
  const float L = red[0];

  for (int i = tid; i < VV / 4; i += 1024) {
    float4 v = ((const float4*)row)[i];
    v.x -= L; v.y -= L; v.z -= L; v.w -= L;
    ((float4*)row)[i] = v;
  }
}

extern "C" void kernel_launch(void* const* d_in, const int* in_sizes, int n_in,
                              void* d_out, int out_size, void* d_ws, size_t ws_size,
                              hipStream_t stream)
{
  const int*   tokens = (const int*)d_in[0];
  const float* hidden = (const float*)d_in[1]; // (3,B,H)
  const float* emb    = (const float*)d_in[2]; // (V,E)
  const float* Wih0 = (const float*)d_in[3];
  const float* Whh0 = (const float*)d_in[4];
  const float* bih0 = (const float*)d_in[5];
  const float* bhh0 = (const float*)d_in[6];
  const float* Wih1 = (const float*)d_in[7];
  const float* Whh1 = (const float*)d_in[8];
  const float* bih1 = (const float*)d_in[9];
  const float* bhh1 = (const float*)d_in[10];
  const float* Wih2 = (const float*)d_in[11];
  const float* Whh2 = (const float*)d_in[12];
  const float* bih2 = (const float*)d_in[13];
  const float* bhh2 = (const float*)d_in[14];
  const float* Wout = (const float*)d_in[15];
  const float* bout = (const float*)d_in[16];

  float* outp = (float*)d_out;
  float* logp = outp;                       // (B,V)
  float* hnew = outp + (size_t)BB * VV;     // (3,B,H)
  float* h0 = hnew;
  float* h1 = hnew + BB * HH;
  float* h2 = hnew + 2 * BB * HH;

  float* gi_flat = (float*)d_ws;                    // (16, 6144)
  float* giP = gi_flat + (size_t)BB * G3H;          // (8,16,6144)
  float* ghP = giP + (size_t)8 * BB * G3H;          // (8,16,6144)
  float* opP = ghP + (size_t)8 * BB * G3H;          // (8,16,32000)

  gru_l0<<<384, 256, 0, stream>>>(emb, tokens, hidden, Wih0, Whh0, gi_flat, ghP);
  gru_epi<false><<<128, 256, 0, stream>>>(gi_flat, nullptr, ghP, bih0, bhh0, hidden, h0);
  gru_l12<<<512, 256, 0, stream>>>(h0, hidden + BB * HH, Wih1, Whh1, giP, ghP);
  gru_epi<true><<<128, 256, 0, stream>>>(nullptr, giP, ghP, bih1, bhh1, hidden + BB * HH, h1);
  gru_l12<<<512, 256, 0, stream>>>(h1, hidden + 2 * BB * HH, Wih2, Whh2, giP, ghP);
  gru_epi<true><<<128, 256, 0, stream>>>(nullptr, giP, ghP, bih2, bhh2, hidden + 2 * BB * HH, h2);
  out_kernel<<<500, 256, 0, stream>>>(h2, Wout, opP);
  lsm_kernel<<<16, 1024, 0, stream>>>(opP, bout, logp);
}